// Round 11
// baseline (201.281 us; speedup 1.0000x reference)
//
#include <hip/hip_runtime.h>
#include <math.h>

#ifndef __has_builtin
#define __has_builtin(x) 0
#endif
#if __has_builtin(__builtin_amdgcn_exp2f)
#define EXP2F(x) __builtin_amdgcn_exp2f(x)
#else
#define EXP2F(x) exp2f(x)
#endif

#define L2E  1.44269504088896340736f
#define RL2E 0.69314718055994530942f

#define NBATCH 2
#define NC 21
#define NP 4096
#define KR 35
#define KS 71

typedef _Float16 half_t;
typedef _Float16 h8 __attribute__((ext_vector_type(8)));
typedef _Float16 h4 __attribute__((ext_vector_type(4)));
typedef float f4 __attribute__((ext_vector_type(4)));
#define MFMA16(a, b, c) __builtin_amdgcn_mfma_f32_16x16x32_f16((a), (b), (c), 0, 0, 0)

// ================= K-gen tiling (R10-proven structure, minus MFMA) ==========
#define KG_PTILE 128       // p per block: 4 waves * 2 mtiles * 16
#define KG_NPT   32
#define KG_SQ    16        // q-chunks of 256
#define KG_CHUNK 256
#define KG_STEPS 8
#define NBKG (NBATCH * KG_NPT * KG_SQ)   // 1024

// ================= GEMM tiling =============================================
#define GM_PTILE 256       // p per block: 4 waves * 4 mtiles * 16
#define GM_NPT   16
#define GM_SQ    16        // q-slices of 256
#define GM_SLICE 256
#define GM_STEPS 8
#define NBGM (NBATCH * GM_NPT * GM_SQ)   // 512
#define NBCONV (NBATCH * NC)             // 42

// partial layout: [qs 16][n 2][pt 16][mt 16][cht 2][lane 64][4] halves
#define SEG_HALVES 256
#define PART_PER_NPT 8192      // 32 segs * 256 halves per (n,pt) per slice

// ---- ws layout (float offsets) ----
#define OFF_QFEAT 0                  // [NB*P][8] fp32 AoS {L*f0..L*f4, h, 0,0}
#define OFF_QSOA  65536              // [6][NB*P] fp32 SoA planes
#define OFF_UT    114688             // [NB*P][24] fp32 log-unary
#define OFF_QSF   311296             // [NB][21][P] fp32 spatial out
#define OFF_G     483328             // [64][64] fp16 band-gaussian
#define OFF_QH16  485376             // [NB][24][P] fp16 planar q
#define OFF_PART  845824             // 4,194,304 halves = 2,097,152 floats
#define OFF_KF    2942976            // K fragments: 33,554,432 halves (67 MB)

// ---- LDS ----
#define LDS_BYTES 27648    // gemm 16896 / conv 27648
#define QLS_STRIDE 264     // halves; R6/R10-proven banking

__global__ __launch_bounds__(256) void setup_kernel(
    const float* __restrict__ unary, const float* __restrict__ ref,
    const float* __restrict__ kstd, float* __restrict__ ws,
    float* __restrict__ outq)
{
    int gid = blockIdx.x * 256 + threadIdx.x;
    if (gid < 4096) {
        float s = 0.f;
        for (int t = -KR; t <= KR; ++t) s += expf(-(float)(t * t) * (1.0f / 72.0f));
        int y = gid >> 6, yp = gid & 63;
        int d = y - yp;
        float v = (d >= -KR && d <= KR) ? expf(-(float)(d * d) * (1.0f / 72.0f)) / s : 0.f;
        ((half_t*)(ws + OFF_G))[gid] = (half_t)v;
    }
    if (gid >= NBATCH * NP) return;
    int n = gid >> 12, p = gid & (NP - 1);
    int y = p >> 6, x = p & 63;
    float k0 = kstd[0], k1 = kstd[1], k2 = kstd[2], k3 = kstd[3], k4 = kstd[4];
    const float* rp = ref + n * 3 * NP + p;
    float f0 = (float)y / k0;
    float f1 = (float)x / k1;
    float f2_ = rp[0]      / k2;
    float f3 = rp[NP]     / k3;
    float f4_ = rp[2 * NP] / k4;
    float sq = f0*f0 + f1*f1 + f2_*f2_ + f3*f3 + f4_*f4_;
    float h  = -0.5f * L2E * sq;       // exp2 exponent offset
    float* qf = ws + OFF_QFEAT + gid * 8;
    qf[0]=L2E*f0; qf[1]=L2E*f1; qf[2]=L2E*f2_; qf[3]=L2E*f3; qf[4]=L2E*f4_;
    qf[5]=h; qf[6]=0.f; qf[7]=0.f;
    float* qs = ws + OFF_QSOA;
    qs[0*8192 + gid] = L2E*f0;  qs[1*8192 + gid] = L2E*f1;
    qs[2*8192 + gid] = L2E*f2_; qs[3*8192 + gid] = L2E*f3;
    qs[4*8192 + gid] = L2E*f4_; qs[5*8192 + gid] = h;

    float U[NC], e[NC];
    const float* up = unary + n * NC * NP + p;
    float m = -1e30f;
    for (int c = 0; c < NC; ++c) {
        float u = up[c * NP];
        u = fminf(fmaxf(u, 1e-5f), 1.0f);
        U[c] = logf(u);
        m = fmaxf(m, U[c]);
    }
    float ssum = 0.f;
    for (int c = 0; c < NC; ++c) { e[c] = EXP2F(L2E * (U[c] - m)); ssum += e[c]; }
    float inv = 1.0f / ssum;
    float* ut = ws + OFF_UT + gid * 24;
    half_t* qh = (half_t*)(ws + OFF_QH16);
    for (int c = 0; c < NC; ++c) {
        float qv = e[c] * inv;
        ut[c] = U[c];
        qh[(n * 24 + c) * NP + p] = (half_t)qv;
        outq[(n * NC + c) * NP + p] = qv;
    }
    ut[21] = 0.f; ut[22] = 0.f; ut[23] = 0.f;
    qh[(n * 24 + 21) * NP + p] = (half_t)0.f;
    qh[(n * 24 + 22) * NP + p] = (half_t)0.f;
    qh[(n * 24 + 23) * NP + p] = (half_t)0.f;
}

// ===== K-gen (once): compute K and store in A-fragment order ===============
// kf layout: [(n*256 + pt16)*128 + qstep][64 lanes][8 halves]  (1 KB tiles)
__global__ __launch_bounds__(256) void kgen_kernel(
    const float* __restrict__ qfeatA,
    const float* __restrict__ qsoa,
    half_t* __restrict__ kf)
{
    __shared__ __align__(16) float qsoaS[6 * KG_CHUNK];   // 6 KB
    int b = blockIdx.x;
    int tid = threadIdx.x;
    int l = tid & 63, w = tid >> 6;
    int n  = b & 1;
    int pt = (b >> 1) & (KG_NPT - 1);
    int s  = b >> 6;                       // 0..15

    for (int i = tid; i < 6 * (KG_CHUNK / 4); i += 256) {
        int d = i >> 6, g = i & 63;
        *(f4*)(qsoaS + d * KG_CHUNK + g * 4) =
            *(const f4*)(qsoa + (size_t)d * 8192 + n * NP + s * KG_CHUNK + g * 4);
    }
    float pf[2][5], ph[2];
    #pragma unroll
    for (int mt = 0; mt < 2; ++mt) {
        const float* fp = qfeatA + (size_t)(n * NP + pt * KG_PTILE + (w * 2 + mt) * 16 + (l & 15)) * 8;
        #pragma unroll
        for (int i = 0; i < 5; ++i) pf[mt][i] = fp[i] * RL2E;
        ph[mt] = fp[5];
    }
    int kq = (l >> 4) * 8;
    __syncthreads();

    for (int step = 0; step < KG_STEPS; ++step) {
        int qbase = step * 32 + kq;
        h8 kv[2];
        #pragma unroll
        for (int hf = 0; hf < 2; ++hf) {
            f4 qf0 = *(const f4*)(qsoaS + 0 * KG_CHUNK + qbase + hf * 4);
            f4 qf1 = *(const f4*)(qsoaS + 1 * KG_CHUNK + qbase + hf * 4);
            f4 qf2 = *(const f4*)(qsoaS + 2 * KG_CHUNK + qbase + hf * 4);
            f4 qf3 = *(const f4*)(qsoaS + 3 * KG_CHUNK + qbase + hf * 4);
            f4 qf4 = *(const f4*)(qsoaS + 4 * KG_CHUNK + qbase + hf * 4);
            f4 qf5 = *(const f4*)(qsoaS + 5 * KG_CHUNK + qbase + hf * 4);
            #pragma unroll
            for (int j2 = 0; j2 < 4; ++j2) {
                float q0 = qf0[j2], q1 = qf1[j2], q2 = qf2[j2];
                float q3 = qf3[j2], q4 = qf4[j2], qh = qf5[j2];
                #pragma unroll
                for (int mt = 0; mt < 2; ++mt) {
                    float e = ph[mt] + qh;
                    e = fmaf(pf[mt][0], q0, e);
                    e = fmaf(pf[mt][1], q1, e);
                    e = fmaf(pf[mt][2], q2, e);
                    e = fmaf(pf[mt][3], q3, e);
                    e = fmaf(pf[mt][4], q4, e);
                    kv[mt][hf * 4 + j2] = (half_t)EXP2F(e);
                }
            }
        }
        int qstep = s * KG_STEPS + step;   // 0..127
        #pragma unroll
        for (int mt = 0; mt < 2; ++mt) {
            int pt16 = pt * 8 + w * 2 + mt;            // 0..255
            size_t tile = ((size_t)(n * 256 + pt16) * 128 + qstep) * 512;
            *(h8*)(kf + tile + l * 8) = kv[mt];        // 1 KB/wave coalesced
        }
    }
}

// ===== L1 per iter: blocks [0,512): K GEMM.  [512,554): separable conv. ====
__global__ __launch_bounds__(256) void gemm_conv_kernel(
    const half_t* __restrict__ kf,
    const half_t* __restrict__ qh16,
    const half_t* __restrict__ gmat,
    half_t* __restrict__ part,
    float* __restrict__ qsf)
{
    __shared__ __align__(16) char lds[LDS_BYTES];
    int b = blockIdx.x;
    int tid = threadIdx.x;
    int l = tid & 63, w = tid >> 6;

    if (b < NBGM) {
        int n  = b & 1;
        int pt = (b >> 1) & (GM_NPT - 1);
        int qs = b >> 5;                           // 0..15
        half_t* qls = (half_t*)lds;                // [32][264] 16896 B

        // stage q-probs fp16 rows 0..20; zero rows 21..31
        for (int i = tid; i < 21 * (GM_SLICE / 8); i += 256) {   // 672 h8
            int c = i >> 5, g = i & 31;
            *(h8*)(qls + c * QLS_STRIDE + g * 8) =
                *(const h8*)(qh16 + (size_t)(n * 24 + c) * NP + qs * GM_SLICE + g * 8);
        }
        for (int i = tid; i < 11 * 33; i += 256) {
            int c = 21 + i / 33, g = i % 33;
            *(h8*)(qls + c * QLS_STRIDE + g * 8) = (h8)(half_t)0.f;
        }
        f4 acc[4][2];
        #pragma unroll
        for (int mt = 0; mt < 4; ++mt) { acc[mt][0] = (f4)0.f; acc[mt][1] = (f4)0.f; }
        int kq = (l >> 4) * 8;
        __syncthreads();

        #pragma unroll 2
        for (int step = 0; step < GM_STEPS; ++step) {
            int qbase = step * 32 + kq;
            int qstep = qs * GM_STEPS + step;      // 0..127
            h8 av[4];
            #pragma unroll
            for (int mt = 0; mt < 4; ++mt) {
                int pt16 = pt * 16 + w * 4 + mt;   // 0..255
                size_t tile = ((size_t)(n * 256 + pt16) * 128 + qstep) * 512;
                av[mt] = *(const h8*)(kf + tile + l * 8);   // coalesced 1 KB
            }
            h8 bf0 = *(const h8*)(qls + (size_t)(l & 15) * QLS_STRIDE + qbase);
            h8 bf1 = *(const h8*)(qls + (size_t)(16 + (l & 15)) * QLS_STRIDE + qbase);
            #pragma unroll
            for (int mt = 0; mt < 4; ++mt) {
                acc[mt][0] = MFMA16(av[mt], bf0, acc[mt][0]);
                acc[mt][1] = MFMA16(av[mt], bf1, acc[mt][1]);
            }
        }
        // epilogue: fp16 C-fragment partials, coalesced b64
        #pragma unroll
        for (int mt = 0; mt < 4; ++mt) {
            #pragma unroll
            for (int cht = 0; cht < 2; ++cht) {
                int segFlat = ((((qs * 2 + n) * GM_NPT + pt) * 16 + (w * 4 + mt)) * 2 + cht);
                h4 hv;
                hv[0] = (half_t)acc[mt][cht][0];
                hv[1] = (half_t)acc[mt][cht][1];
                hv[2] = (half_t)acc[mt][cht][2];
                hv[3] = (half_t)acc[mt][cht][3];
                *(h4*)(part + (size_t)segFlat * SEG_HALVES + l * 4) = hv;
            }
        }
    } else {
        // ---- conv block: one (n,c); qsf = G * Q * G ----
        int cb = b - NBGM;
        int n = cb / NC, c = cb % NC;
        half_t* qt = (half_t*)lds;
        half_t* gl = (half_t*)(lds + 9216);
        half_t* dl = (half_t*)(lds + 18432);

        for (int i = tid; i < 512; i += 256) {
            int row = i >> 3, g = i & 7;
            *(h8*)(gl + row * 72 + g * 8) = *(const h8*)(gmat + row * 64 + g * 8);
        }
        const half_t* qsrc = qh16 + (size_t)(n * 24 + c) * NP;
        for (int i = tid; i < 512; i += 256) {
            int row = i >> 3, g = i & 7;
            h8 v = *(const h8*)(qsrc + row * 64 + g * 8);
            #pragma unroll
            for (int k = 0; k < 8; ++k) qt[(g * 8 + k) * 72 + row] = v[k];
        }
        __syncthreads();

        int m0 = w * 16;
        f4 acc1[4];
        #pragma unroll
        for (int nt = 0; nt < 4; ++nt) acc1[nt] = (f4)0.f;
        #pragma unroll
        for (int ks = 0; ks < 2; ++ks) {
            h8 af = *(const h8*)(gl + (size_t)(m0 + (l & 15)) * 72 + ks * 32 + (l >> 4) * 8);
            #pragma unroll
            for (int nt = 0; nt < 4; ++nt) {
                h8 bf = *(const h8*)(qt + (size_t)(nt * 16 + (l & 15)) * 72 + ks * 32 + (l >> 4) * 8);
                acc1[nt] = MFMA16(af, bf, acc1[nt]);
            }
        }
        #pragma unroll
        for (int nt = 0; nt < 4; ++nt)
            #pragma unroll
            for (int r = 0; r < 4; ++r)
                dl[(size_t)(m0 + (l >> 4) * 4 + r) * 72 + nt * 16 + (l & 15)] = (half_t)acc1[nt][r];
        __syncthreads();

        f4 acc2[4];
        #pragma unroll
        for (int nt = 0; nt < 4; ++nt) acc2[nt] = (f4)0.f;
        #pragma unroll
        for (int ks = 0; ks < 2; ++ks) {
            h8 af = *(const h8*)(dl + (size_t)(m0 + (l & 15)) * 72 + ks * 32 + (l >> 4) * 8);
            #pragma unroll
            for (int nt = 0; nt < 4; ++nt) {
                h8 bf = *(const h8*)(gl + (size_t)(nt * 16 + (l & 15)) * 72 + ks * 32 + (l >> 4) * 8);
                acc2[nt] = MFMA16(af, bf, acc2[nt]);
            }
        }
        float* dst = qsf + (size_t)(n * NC + c) * NP;
        #pragma unroll
        for (int nt = 0; nt < 4; ++nt)
            #pragma unroll
            for (int r = 0; r < 4; ++r)
                dst[(size_t)(m0 + (l >> 4) * 4 + r) * 64 + nt * 16 + (l & 15)] = acc2[nt][r];
    }
}

// ===== L2+L3 merged: reduce 16 slices + per-pixel softmax ==================
// 32 blocks, one per (n, pt of 256 p)
__global__ __launch_bounds__(256) void reduce_update_kernel(
    const half_t* __restrict__ part, const float* __restrict__ ut_,
    const float* __restrict__ qsf, float* __restrict__ outq,
    half_t* __restrict__ qh16)
{
    __shared__ float red[PART_PER_NPT];   // 32 KB
    int rb = blockIdx.x;                  // [0,32)
    int tid = threadIdx.x;
    int n = rb & 1, pt = rb >> 1;

    float acc[32];
    #pragma unroll
    for (int k = 0; k < 32; ++k) acc[k] = 0.f;
    for (int s = 0; s < GM_SQ; ++s) {
        size_t base = (size_t)((s * 2 + n) * GM_NPT + pt) * PART_PER_NPT;
        #pragma unroll
        for (int k = 0; k < 8; ++k) {
            h4 v = *(const h4*)(part + base + (size_t)(k * 256 + tid) * 4);
            acc[k*4+0] += (float)v[0]; acc[k*4+1] += (float)v[1];
            acc[k*4+2] += (float)v[2]; acc[k*4+3] += (float)v[3];
        }
    }
    #pragma unroll
    for (int k = 0; k < 8; ++k)
        *(f4*)(red + (k * 256 + tid) * 4) =
            (f4){acc[k*4+0], acc[k*4+1], acc[k*4+2], acc[k*4+3]};
    __syncthreads();

    {
        int pp = tid;                      // 0..255
        int p = pt * GM_PTILE + pp;
        int gid = n * NP + p;
        int mt_g = pp >> 4;                // 0..15
        int mrow = pp & 15;
        int lg = mrow >> 2, reg = mrow & 3;
        int segL = mt_g * 2;               // + cht

        float lg_[NC], e[NC];
        const float* ut = ut_ + (size_t)gid * 24;
        const float* qs = qsf + (size_t)n * NC * NP + p;
        float m = -1e30f;
        #pragma unroll
        for (int c = 0; c < NC; ++c) {
            int cht = c >> 4, chL = c & 15;
            float qb = red[(segL + cht) * 256 + (lg * 16 + chL) * 4 + reg];
            float li = ut[c] + 4.0f * qb + 2.0f * qs[c * NP];
            lg_[c] = li;
            m = fmaxf(m, li);
        }
        float ssum = 0.f;
        #pragma unroll
        for (int c = 0; c < NC; ++c) { e[c] = EXP2F(L2E * (lg_[c] - m)); ssum += e[c]; }
        float inv = 1.0f / ssum;
        #pragma unroll
        for (int c = 0; c < NC; ++c) {
            float qv = e[c] * inv;
            outq[(size_t)(n * NC + c) * NP + p] = qv;
            qh16[(size_t)(n * 24 + c) * NP + p] = (half_t)qv;
        }
    }
}

extern "C" void kernel_launch(void* const* d_in, const int* in_sizes, int n_in,
                              void* d_out, int out_size, void* d_ws, size_t ws_size,
                              hipStream_t stream)
{
    const float* unary = (const float*)d_in[0];
    const float* ref   = (const float*)d_in[1];
    const float* kstd  = (const float*)d_in[3];
    float* ws   = (float*)d_ws;
    float* outq = (float*)d_out;

    const float*  qfeatA = ws + OFF_QFEAT;
    const float*  qsoa   = ws + OFF_QSOA;
    float*        ut     = ws + OFF_UT;
    float*        qsf    = ws + OFF_QSF;
    const half_t* gmat   = (const half_t*)(ws + OFF_G);
    half_t*       qh16   = (half_t*)(ws + OFF_QH16);
    half_t*       part   = (half_t*)(ws + OFF_PART);
    half_t*       kf     = (half_t*)(ws + OFF_KF);

    setup_kernel<<<32, 256, 0, stream>>>(unary, ref, kstd, ws, outq);
    kgen_kernel<<<NBKG, 256, 0, stream>>>(qfeatA, qsoa, kf);
    for (int it = 0; it < 5; ++it) {
        gemm_conv_kernel<<<NBGM + NBCONV, 256, 0, stream>>>(
            kf, qh16, gmat, part, qsf);
        reduce_update_kernel<<<32, 256, 0, stream>>>(part, ut, qsf, outq, qh16);
    }
}

// Round 12
// 172.507 us; speedup vs baseline: 1.1668x; 1.1668x over previous
//
#include <hip/hip_runtime.h>
#include <math.h>

#ifndef __has_builtin
#define __has_builtin(x) 0
#endif
#if __has_builtin(__builtin_amdgcn_exp2f)
#define EXP2F(x) __builtin_amdgcn_exp2f(x)
#else
#define EXP2F(x) exp2f(x)
#endif

#define L2E  1.44269504088896340736f
#define RL2E 0.69314718055994530942f

#define NBATCH 2
#define NC 21
#define NP 4096
#define KR 35
#define KS 71

typedef _Float16 half_t;
typedef _Float16 h8 __attribute__((ext_vector_type(8)));
typedef _Float16 h4 __attribute__((ext_vector_type(4)));
typedef float f4 __attribute__((ext_vector_type(4)));
#define MFMA16(a, b, c) __builtin_amdgcn_mfma_f32_16x16x32_f16((a), (b), (c), 0, 0, 0)

// ---- tiling: 4 m-tiles/wave + clean SoA feature reads ----
#define PTILE 256          // p per block: 4 waves * 4 mtiles * 16
#define NPT   16
#define SQ    16           // q-chunks of 256
#define CHUNK 256
#define STEPS 8
#define NBBIL (NBATCH * NPT * SQ)   // 512
#define NBCONV (NBATCH * NC)        // 42

// partial layout (R11-proven): [qs 16][n 2][pt 16][mt 16][cht 2][lane 64][4]
#define SEG_HALVES 256
#define PART_PER_NPT 8192

// ---- ws layout (float offsets) ----
#define OFF_QFEAT 0                  // [NB*P][8] fp32 AoS {L*f0..L*f4, h, 0,0}
#define OFF_QSOA  65536              // [6][NB*P] fp32 SoA planes
#define OFF_UT    114688             // [NB*P][24] fp32 log-unary
#define OFF_QSF   311296             // [NB][21][P] fp32 spatial out
#define OFF_G     483328             // [64][64] fp16 band-gaussian
#define OFF_QH16  485376             // [NB][24][P] fp16 planar q
#define OFF_PART  845824             // [SQ][1024 segs][256] fp16 partials

// ---- LDS: bilat 23040 B (SoA 6144 + qls 16896), conv 27648 B ----
#define LDS_BYTES 27648
#define QLS_STRIDE 264

__global__ __launch_bounds__(256) void setup_kernel(
    const float* __restrict__ unary, const float* __restrict__ ref,
    const float* __restrict__ kstd, float* __restrict__ ws,
    float* __restrict__ outq)
{
    int gid = blockIdx.x * 256 + threadIdx.x;
    if (gid < 4096) {
        float s = 0.f;
        for (int t = -KR; t <= KR; ++t) s += expf(-(float)(t * t) * (1.0f / 72.0f));
        int y = gid >> 6, yp = gid & 63;
        int d = y - yp;
        float v = (d >= -KR && d <= KR) ? expf(-(float)(d * d) * (1.0f / 72.0f)) / s : 0.f;
        ((half_t*)(ws + OFF_G))[gid] = (half_t)v;
    }
    if (gid >= NBATCH * NP) return;
    int n = gid >> 12, p = gid & (NP - 1);
    int y = p >> 6, x = p & 63;
    float k0 = kstd[0], k1 = kstd[1], k2 = kstd[2], k3 = kstd[3], k4 = kstd[4];
    const float* rp = ref + n * 3 * NP + p;
    float f0 = (float)y / k0;
    float f1 = (float)x / k1;
    float f2_ = rp[0]      / k2;
    float f3 = rp[NP]     / k3;
    float f4_ = rp[2 * NP] / k4;
    float sq = f0*f0 + f1*f1 + f2_*f2_ + f3*f3 + f4_*f4_;
    float h  = -0.5f * L2E * sq;       // exp2 exponent offset
    float* qf = ws + OFF_QFEAT + gid * 8;
    qf[0]=L2E*f0; qf[1]=L2E*f1; qf[2]=L2E*f2_; qf[3]=L2E*f3; qf[4]=L2E*f4_;
    qf[5]=h; qf[6]=0.f; qf[7]=0.f;
    float* qs = ws + OFF_QSOA;
    qs[0*8192 + gid] = L2E*f0;  qs[1*8192 + gid] = L2E*f1;
    qs[2*8192 + gid] = L2E*f2_; qs[3*8192 + gid] = L2E*f3;
    qs[4*8192 + gid] = L2E*f4_; qs[5*8192 + gid] = h;

    float U[NC], e[NC];
    const float* up = unary + n * NC * NP + p;
    float m = -1e30f;
    for (int c = 0; c < NC; ++c) {
        float u = up[c * NP];
        u = fminf(fmaxf(u, 1e-5f), 1.0f);
        U[c] = logf(u);
        m = fmaxf(m, U[c]);
    }
    float ssum = 0.f;
    for (int c = 0; c < NC; ++c) { e[c] = EXP2F(L2E * (U[c] - m)); ssum += e[c]; }
    float inv = 1.0f / ssum;
    float* ut = ws + OFF_UT + gid * 24;
    half_t* qh = (half_t*)(ws + OFF_QH16);
    for (int c = 0; c < NC; ++c) {
        float qv = e[c] * inv;
        ut[c] = U[c];
        qh[(n * 24 + c) * NP + p] = (half_t)qv;
        outq[(n * NC + c) * NP + p] = qv;
    }
    ut[21] = 0.f; ut[22] = 0.f; ut[23] = 0.f;
    qh[(n * 24 + 21) * NP + p] = (half_t)0.f;
    qh[(n * 24 + 22) * NP + p] = (half_t)0.f;
    qh[(n * 24 + 23) * NP + p] = (half_t)0.f;
}

// L1: blocks [0,512): bilateral (in-register K, 4 mt/wave).  [512,554): conv.
__global__ __launch_bounds__(256) void bilat_conv_kernel(
    const float* __restrict__ qfeatA,
    const float* __restrict__ qsoa,
    const half_t* __restrict__ qh16,
    const half_t* __restrict__ gmat,
    half_t* __restrict__ part,
    float* __restrict__ qsf)
{
    __shared__ __align__(16) char lds[LDS_BYTES];
    int b = blockIdx.x;
    int tid = threadIdx.x;
    int l = tid & 63, w = tid >> 6;

    if (b < NBBIL) {
        int n  = b & 1;
        int pt = (b >> 1) & (NPT - 1);
        int qs = b >> 5;                           // 0..15
        float*  qsoaS = (float*)lds;               // [6][256]  6 KB
        half_t* qls   = (half_t*)(lds + 6144);     // [32][264] 16896 B

        // stage SoA q-features
        for (int i = tid; i < 6 * (CHUNK / 4); i += 256) {
            int d = i >> 6, g = i & 63;
            *(f4*)(qsoaS + d * CHUNK + g * 4) =
                *(const f4*)(qsoa + (size_t)d * 8192 + n * NP + qs * CHUNK + g * 4);
        }
        // stage q-probs fp16 rows 0..20; zero rows 21..31
        for (int i = tid; i < 21 * (CHUNK / 8); i += 256) {
            int c = i >> 5, g = i & 31;
            *(h8*)(qls + c * QLS_STRIDE + g * 8) =
                *(const h8*)(qh16 + (size_t)(n * 24 + c) * NP + qs * CHUNK + g * 8);
        }
        for (int i = tid; i < 11 * 33; i += 256) {
            int c = 21 + i / 33, g = i % 33;
            *(h8*)(qls + c * QLS_STRIDE + g * 8) = (h8)(half_t)0.f;
        }
        // p-side features: wave w owns m-tiles w*4..w*4+3; lane row = l&15
        float pf[4][5], ph[4];
        #pragma unroll
        for (int mt = 0; mt < 4; ++mt) {
            const float* fp = qfeatA + (size_t)(n * NP + pt * PTILE + (w * 4 + mt) * 16 + (l & 15)) * 8;
            #pragma unroll
            for (int i = 0; i < 5; ++i) pf[mt][i] = fp[i] * RL2E;
            ph[mt] = fp[5];
        }
        f4 acc[4][2];
        #pragma unroll
        for (int mt = 0; mt < 4; ++mt) { acc[mt][0] = (f4)0.f; acc[mt][1] = (f4)0.f; }
        int kq = (l >> 4) * 8;
        __syncthreads();

        for (int step = 0; step < STEPS; ++step) {
            int qbase = step * 32 + kq;
            // ---- hoisted loads: all feature quads + B-fragments up front ----
            f4 qd[6][2];
            #pragma unroll
            for (int d = 0; d < 6; ++d) {
                qd[d][0] = *(const f4*)(qsoaS + d * CHUNK + qbase);
                qd[d][1] = *(const f4*)(qsoaS + d * CHUNK + qbase + 4);
            }
            h8 bf0 = *(const h8*)(qls + (size_t)(l & 15) * QLS_STRIDE + qbase);
            h8 bf1 = *(const h8*)(qls + (size_t)(16 + (l & 15)) * QLS_STRIDE + qbase);
            // ---- exponent + exp block (32 independent chains) ----
            h8 kv[4];
            #pragma unroll
            for (int hf = 0; hf < 2; ++hf) {
                #pragma unroll
                for (int j2 = 0; j2 < 4; ++j2) {
                    float q0 = qd[0][hf][j2], q1 = qd[1][hf][j2], q2 = qd[2][hf][j2];
                    float q3 = qd[3][hf][j2], q4 = qd[4][hf][j2], qh = qd[5][hf][j2];
                    #pragma unroll
                    for (int mt = 0; mt < 4; ++mt) {
                        float e = ph[mt] + qh;
                        e = fmaf(pf[mt][0], q0, e);
                        e = fmaf(pf[mt][1], q1, e);
                        e = fmaf(pf[mt][2], q2, e);
                        e = fmaf(pf[mt][3], q3, e);
                        e = fmaf(pf[mt][4], q4, e);
                        kv[mt][hf * 4 + j2] = (half_t)EXP2F(e);
                    }
                }
            }
            // ---- MFMA block ----
            #pragma unroll
            for (int mt = 0; mt < 4; ++mt) {
                acc[mt][0] = MFMA16(kv[mt], bf0, acc[mt][0]);
                acc[mt][1] = MFMA16(kv[mt], bf1, acc[mt][1]);
            }
        }
        // epilogue (R11-proven layout): fp16 C-fragment partials
        #pragma unroll
        for (int mt = 0; mt < 4; ++mt) {
            #pragma unroll
            for (int cht = 0; cht < 2; ++cht) {
                int segFlat = ((((qs * 2 + n) * NPT + pt) * 16 + (w * 4 + mt)) * 2 + cht);
                h4 hv;
                hv[0] = (half_t)acc[mt][cht][0];
                hv[1] = (half_t)acc[mt][cht][1];
                hv[2] = (half_t)acc[mt][cht][2];
                hv[3] = (half_t)acc[mt][cht][3];
                *(h4*)(part + (size_t)segFlat * SEG_HALVES + l * 4) = hv;
            }
        }
    } else {
        // ---- conv block: one (n,c); qsf = G * Q * G ----
        int cb = b - NBBIL;
        int n = cb / NC, c = cb % NC;
        half_t* qt = (half_t*)lds;
        half_t* gl = (half_t*)(lds + 9216);
        half_t* dl = (half_t*)(lds + 18432);

        for (int i = tid; i < 512; i += 256) {
            int row = i >> 3, g = i & 7;
            *(h8*)(gl + row * 72 + g * 8) = *(const h8*)(gmat + row * 64 + g * 8);
        }
        const half_t* qsrc = qh16 + (size_t)(n * 24 + c) * NP;
        for (int i = tid; i < 512; i += 256) {
            int row = i >> 3, g = i & 7;
            h8 v = *(const h8*)(qsrc + row * 64 + g * 8);
            #pragma unroll
            for (int k = 0; k < 8; ++k) qt[(g * 8 + k) * 72 + row] = v[k];
        }
        __syncthreads();

        int m0 = w * 16;
        f4 acc1[4];
        #pragma unroll
        for (int nt = 0; nt < 4; ++nt) acc1[nt] = (f4)0.f;
        #pragma unroll
        for (int ks = 0; ks < 2; ++ks) {
            h8 af = *(const h8*)(gl + (size_t)(m0 + (l & 15)) * 72 + ks * 32 + (l >> 4) * 8);
            #pragma unroll
            for (int nt = 0; nt < 4; ++nt) {
                h8 bf = *(const h8*)(qt + (size_t)(nt * 16 + (l & 15)) * 72 + ks * 32 + (l >> 4) * 8);
                acc1[nt] = MFMA16(af, bf, acc1[nt]);
            }
        }
        #pragma unroll
        for (int nt = 0; nt < 4; ++nt)
            #pragma unroll
            for (int r = 0; r < 4; ++r)
                dl[(size_t)(m0 + (l >> 4) * 4 + r) * 72 + nt * 16 + (l & 15)] = (half_t)acc1[nt][r];
        __syncthreads();

        f4 acc2[4];
        #pragma unroll
        for (int nt = 0; nt < 4; ++nt) acc2[nt] = (f4)0.f;
        #pragma unroll
        for (int ks = 0; ks < 2; ++ks) {
            h8 af = *(const h8*)(dl + (size_t)(m0 + (l & 15)) * 72 + ks * 32 + (l >> 4) * 8);
            #pragma unroll
            for (int nt = 0; nt < 4; ++nt) {
                h8 bf = *(const h8*)(gl + (size_t)(nt * 16 + (l & 15)) * 72 + ks * 32 + (l >> 4) * 8);
                acc2[nt] = MFMA16(af, bf, acc2[nt]);
            }
        }
        float* dst = qsf + (size_t)(n * NC + c) * NP;
        #pragma unroll
        for (int nt = 0; nt < 4; ++nt)
            #pragma unroll
            for (int r = 0; r < 4; ++r)
                dst[(size_t)(m0 + (l >> 4) * 4 + r) * 64 + nt * 16 + (l & 15)] = acc2[nt][r];
    }
}

// L2+L3 merged (R11-proven): 32 blocks, one per (n, pt of 256 p)
__global__ __launch_bounds__(256) void reduce_update_kernel(
    const half_t* __restrict__ part, const float* __restrict__ ut_,
    const float* __restrict__ qsf, float* __restrict__ outq,
    half_t* __restrict__ qh16)
{
    __shared__ float red[PART_PER_NPT];   // 32 KB
    int rb = blockIdx.x;                  // [0,32)
    int tid = threadIdx.x;
    int n = rb & 1, pt = rb >> 1;

    float acc[32];
    #pragma unroll
    for (int k = 0; k < 32; ++k) acc[k] = 0.f;
    for (int s = 0; s < SQ; ++s) {
        size_t base = (size_t)((s * 2 + n) * NPT + pt) * PART_PER_NPT;
        #pragma unroll
        for (int k = 0; k < 8; ++k) {
            h4 v = *(const h4*)(part + base + (size_t)(k * 256 + tid) * 4);
            acc[k*4+0] += (float)v[0]; acc[k*4+1] += (float)v[1];
            acc[k*4+2] += (float)v[2]; acc[k*4+3] += (float)v[3];
        }
    }
    #pragma unroll
    for (int k = 0; k < 8; ++k)
        *(f4*)(red + (k * 256 + tid) * 4) =
            (f4){acc[k*4+0], acc[k*4+1], acc[k*4+2], acc[k*4+3]};
    __syncthreads();

    {
        int pp = tid;                      // 0..255
        int p = pt * PTILE + pp;
        int gid = n * NP + p;
        int mt_g = pp >> 4;                // 0..15
        int mrow = pp & 15;
        int lg = mrow >> 2, reg = mrow & 3;
        int segL = mt_g * 2;               // + cht

        float lg_[NC], e[NC];
        const float* ut = ut_ + (size_t)gid * 24;
        const float* qsp = qsf + (size_t)n * NC * NP + p;
        float m = -1e30f;
        #pragma unroll
        for (int c = 0; c < NC; ++c) {
            int cht = c >> 4, chL = c & 15;
            float qb = red[(segL + cht) * 256 + (lg * 16 + chL) * 4 + reg];
            float li = ut[c] + 4.0f * qb + 2.0f * qsp[c * NP];
            lg_[c] = li;
            m = fmaxf(m, li);
        }
        float ssum = 0.f;
        #pragma unroll
        for (int c = 0; c < NC; ++c) { e[c] = EXP2F(L2E * (lg_[c] - m)); ssum += e[c]; }
        float inv = 1.0f / ssum;
        #pragma unroll
        for (int c = 0; c < NC; ++c) {
            float qv = e[c] * inv;
            outq[(size_t)(n * NC + c) * NP + p] = qv;
            qh16[(size_t)(n * 24 + c) * NP + p] = (half_t)qv;
        }
    }
}

extern "C" void kernel_launch(void* const* d_in, const int* in_sizes, int n_in,
                              void* d_out, int out_size, void* d_ws, size_t ws_size,
                              hipStream_t stream)
{
    const float* unary = (const float*)d_in[0];
    const float* ref   = (const float*)d_in[1];
    const float* kstd  = (const float*)d_in[3];
    float* ws   = (float*)d_ws;
    float* outq = (float*)d_out;

    const float*  qfeatA = ws + OFF_QFEAT;
    const float*  qsoa   = ws + OFF_QSOA;
    float*        ut     = ws + OFF_UT;
    float*        qsf    = ws + OFF_QSF;
    const half_t* gmat   = (const half_t*)(ws + OFF_G);
    half_t*       qh16   = (half_t*)(ws + OFF_QH16);
    half_t*       part   = (half_t*)(ws + OFF_PART);

    setup_kernel<<<32, 256, 0, stream>>>(unary, ref, kstd, ws, outq);
    for (int it = 0; it < 5; ++it) {
        bilat_conv_kernel<<<NBBIL + NBCONV, 256, 0, stream>>>(
            qfeatA, qsoa, qh16, gmat, part, qsf);
        reduce_update_kernel<<<32, 256, 0, stream>>>(part, ut, qsf, outq, qh16);
    }
}

// Round 14
// 155.486 us; speedup vs baseline: 1.2945x; 1.1095x over previous
//
#include <hip/hip_runtime.h>
#include <math.h>

#ifndef __has_builtin
#define __has_builtin(x) 0
#endif
#if __has_builtin(__builtin_amdgcn_exp2f)
#define EXP2F(x) __builtin_amdgcn_exp2f(x)
#else
#define EXP2F(x) exp2f(x)
#endif

#define L2E  1.44269504088896340736f
#define RL2E 0.69314718055994530942f

#define NBATCH 2
#define NC 21
#define NP 4096
#define KR 35
#define KS 71

typedef _Float16 half_t;
typedef _Float16 h8 __attribute__((ext_vector_type(8)));
typedef _Float16 h4 __attribute__((ext_vector_type(4)));
typedef float f4 __attribute__((ext_vector_type(4)));
typedef float f2 __attribute__((ext_vector_type(2)));
#define MFMA16(a, b, c) __builtin_amdgcn_mfma_f32_16x16x32_f16((a), (b), (c), 0, 0, 0)

// packed fp32 math via inline asm (builtin lowering NaN'd — R8/R13)
static __device__ __forceinline__ f2 pk_fma(f2 a, f2 b, f2 c) {
    f2 d;
    asm volatile("v_pk_fma_f32 %0, %1, %2, %3" : "=v"(d) : "v"(a), "v"(b), "v"(c));
    return d;
}
static __device__ __forceinline__ f2 pk_add(f2 a, f2 b) {
    f2 d;
    asm volatile("v_pk_add_f32 %0, %1, %2" : "=v"(d) : "v"(a), "v"(b));
    return d;
}

// ---- tiling: R10-proven (best measured: 159.5 us) ----
#define PTILE 128          // p per block (2 m-tiles per wave)
#define NPT   32
#define SQ    16           // q-splits -> chunk = 256 q
#define CHUNK 256
#define STEPS 8            // CHUNK/32
#define NBBIL (NBATCH * NPT * SQ)   // 1024
#define NBCONV (NBATCH * NC)        // 42
#define SEGS_PER_S 1024
#define SEG_HALVES 256

// ---- ws layout (float offsets) ----
#define OFF_QFEAT 0                  // [NB*P][8] fp32 AoS {L*f0..L*f4, h, 0,0}
#define OFF_QSOA  65536              // [6][NB*P] fp32 SoA planes
#define OFF_UT    114688             // [NB*P][24] fp32 log-unary
#define OFF_QSF   311296             // [NB][21][P] fp32 spatial out
#define OFF_G     483328             // [64][64] fp16 band-gaussian
#define OFF_QH16  485376             // [NB][24][P] fp16 planar q
#define OFF_PART  845824             // [SQ][1024 segs][256] fp16 partials

// ---- LDS: bilat 23040 B (SoA 6144 + qls 16896), conv 27648 B ----
#define LDS_BYTES 27648
#define QLS_STRIDE 264     // halves (256 data + 8 pad) — R6-proven banking

__global__ __launch_bounds__(256) void setup_kernel(
    const float* __restrict__ unary, const float* __restrict__ ref,
    const float* __restrict__ kstd, float* __restrict__ ws,
    float* __restrict__ outq)
{
    int gid = blockIdx.x * 256 + threadIdx.x;
    if (gid < 4096) {
        float s = 0.f;
        for (int t = -KR; t <= KR; ++t) s += expf(-(float)(t * t) * (1.0f / 72.0f));
        int y = gid >> 6, yp = gid & 63;
        int d = y - yp;
        float v = (d >= -KR && d <= KR) ? expf(-(float)(d * d) * (1.0f / 72.0f)) / s : 0.f;
        ((half_t*)(ws + OFF_G))[gid] = (half_t)v;
    }
    if (gid >= NBATCH * NP) return;
    int n = gid >> 12, p = gid & (NP - 1);
    int y = p >> 6, x = p & 63;
    float k0 = kstd[0], k1 = kstd[1], k2 = kstd[2], k3 = kstd[3], k4 = kstd[4];
    const float* rp = ref + n * 3 * NP + p;
    float f0 = (float)y / k0;
    float f1 = (float)x / k1;
    float f2_ = rp[0]      / k2;
    float f3 = rp[NP]     / k3;
    float f4_ = rp[2 * NP] / k4;
    float sq = f0*f0 + f1*f1 + f2_*f2_ + f3*f3 + f4_*f4_;
    float h  = -0.5f * L2E * sq;       // exp2 exponent offset
    float* qf = ws + OFF_QFEAT + gid * 8;
    qf[0]=L2E*f0; qf[1]=L2E*f1; qf[2]=L2E*f2_; qf[3]=L2E*f3; qf[4]=L2E*f4_;
    qf[5]=h; qf[6]=0.f; qf[7]=0.f;
    float* qs = ws + OFF_QSOA;
    qs[0*8192 + gid] = L2E*f0;  qs[1*8192 + gid] = L2E*f1;
    qs[2*8192 + gid] = L2E*f2_; qs[3*8192 + gid] = L2E*f3;
    qs[4*8192 + gid] = L2E*f4_; qs[5*8192 + gid] = h;

    float U[NC], e[NC];
    const float* up = unary + n * NC * NP + p;
    float m = -1e30f;
    for (int c = 0; c < NC; ++c) {
        float u = up[c * NP];
        u = fminf(fmaxf(u, 1e-5f), 1.0f);
        U[c] = logf(u);
        m = fmaxf(m, U[c]);
    }
    float ssum = 0.f;
    for (int c = 0; c < NC; ++c) { e[c] = EXP2F(L2E * (U[c] - m)); ssum += e[c]; }
    float inv = 1.0f / ssum;
    float* ut = ws + OFF_UT + gid * 24;
    half_t* qh = (half_t*)(ws + OFF_QH16);
    for (int c = 0; c < NC; ++c) {
        float qv = e[c] * inv;
        ut[c] = U[c];
        qh[(n * 24 + c) * NP + p] = (half_t)qv;
        outq[(n * NC + c) * NP + p] = qv;
    }
    ut[21] = 0.f; ut[22] = 0.f; ut[23] = 0.f;
    qh[(n * 24 + 21) * NP + p] = (half_t)0.f;
    qh[(n * 24 + 22) * NP + p] = (half_t)0.f;
    qh[(n * 24 + 23) * NP + p] = (half_t)0.f;
}

// L1: blocks [0,1024): bilateral.  blocks [1024,1066): separable conv.
__global__ __launch_bounds__(256) void bilat_conv_kernel(
    const float* __restrict__ qfeatA,     // AoS (p side)
    const float* __restrict__ qsoa,       // SoA planes (q side)
    const half_t* __restrict__ qh16,
    const half_t* __restrict__ gmat,
    half_t* __restrict__ part,
    float* __restrict__ qsf)
{
    __shared__ __align__(16) char lds[LDS_BYTES];
    int b = blockIdx.x;
    int tid = threadIdx.x;
    int l = tid & 63, w = tid >> 6;

    if (b < NBBIL) {
        int n  = b & 1;
        int pt = (b >> 1) & (NPT - 1);
        int s  = b >> 6;                           // 0..15
        float*  qsoaS = (float*)lds;               // [6][256]  6 KB
        half_t* qls   = (half_t*)(lds + 6144);     // [32][264] 16896 B

        // stage SoA q-features (coalesced per plane)
        for (int i = tid; i < 6 * (CHUNK / 4); i += 256) {   // 384 float4
            int d = i >> 6, g = i & 63;
            *(f4*)(qsoaS + d * CHUNK + g * 4) =
                *(const f4*)(qsoa + (size_t)d * 8192 + n * NP + s * CHUNK + g * 4);
        }
        // stage q-probs fp16 rows 0..20; zero rows 21..31
        for (int i = tid; i < 21 * (CHUNK / 8); i += 256) {  // 672 h8
            int c = i >> 5, g = i & 31;
            *(h8*)(qls + c * QLS_STRIDE + g * 8) =
                *(const h8*)(qh16 + (size_t)(n * 24 + c) * NP + s * CHUNK + g * 8);
        }
        for (int i = tid; i < 11 * 33; i += 256) {           // 363 h8 zeros
            int c = 21 + i / 33, g = i % 33;
            *(h8*)(qls + c * QLS_STRIDE + g * 8) = (h8)(half_t)0.f;
        }
        // p-side features: wave w owns m-tiles w*2, w*2+1; lane row = l&15
        // broadcast pairs hoisted for packed math
        f2 pf2[2][5], ph2[2];
        #pragma unroll
        for (int mt = 0; mt < 2; ++mt) {
            const float* fp = qfeatA + (size_t)(n * NP + pt * PTILE + (w * 2 + mt) * 16 + (l & 15)) * 8;
            #pragma unroll
            for (int i = 0; i < 5; ++i) {
                float v = fp[i] * RL2E;
                pf2[mt][i] = (f2){v, v};
            }
            ph2[mt] = (f2){fp[5], fp[5]};
        }
        f4 acc[2][2];
        #pragma unroll
        for (int mt = 0; mt < 2; ++mt) { acc[mt][0] = (f4)0.f; acc[mt][1] = (f4)0.f; }
        int kq = (l >> 4) * 8;
        __syncthreads();

        for (int step = 0; step < STEPS; ++step) {
            int qbase = step * 32 + kq;
            h8 kv[2];
            #pragma unroll
            for (int hf = 0; hf < 2; ++hf) {
                // conflict-free b128 quad reads: this lane's 4 q's, all 6 features
                f4 qf0 = *(const f4*)(qsoaS + 0 * CHUNK + qbase + hf * 4);
                f4 qf1 = *(const f4*)(qsoaS + 1 * CHUNK + qbase + hf * 4);
                f4 qf2 = *(const f4*)(qsoaS + 2 * CHUNK + qbase + hf * 4);
                f4 qf3 = *(const f4*)(qsoaS + 3 * CHUNK + qbase + hf * 4);
                f4 qf4 = *(const f4*)(qsoaS + 4 * CHUNK + qbase + hf * 4);
                f4 qf5 = *(const f4*)(qsoaS + 5 * CHUNK + qbase + hf * 4);
                // packed fp32 fma via asm: two q's per instruction
                #pragma unroll
                for (int pr = 0; pr < 2; ++pr) {
                    f2 q0 = {qf0[2*pr], qf0[2*pr+1]};
                    f2 q1 = {qf1[2*pr], qf1[2*pr+1]};
                    f2 q2 = {qf2[2*pr], qf2[2*pr+1]};
                    f2 q3 = {qf3[2*pr], qf3[2*pr+1]};
                    f2 q4 = {qf4[2*pr], qf4[2*pr+1]};
                    f2 qh2 = {qf5[2*pr], qf5[2*pr+1]};
                    #pragma unroll
                    for (int mt = 0; mt < 2; ++mt) {
                        f2 e = pk_add(qh2, ph2[mt]);
                        e = pk_fma(pf2[mt][0], q0, e);
                        e = pk_fma(pf2[mt][1], q1, e);
                        e = pk_fma(pf2[mt][2], q2, e);
                        e = pk_fma(pf2[mt][3], q3, e);
                        e = pk_fma(pf2[mt][4], q4, e);
                        kv[mt][hf * 4 + pr * 2]     = (half_t)EXP2F(e[0]);
                        kv[mt][hf * 4 + pr * 2 + 1] = (half_t)EXP2F(e[1]);
                    }
                }
            }
            h8 bf0 = *(const h8*)(qls + (size_t)(l & 15) * QLS_STRIDE + qbase);
            h8 bf1 = *(const h8*)(qls + (size_t)(16 + (l & 15)) * QLS_STRIDE + qbase);
            #pragma unroll
            for (int mt = 0; mt < 2; ++mt) {
                acc[mt][0] = MFMA16(kv[mt], bf0, acc[mt][0]);
                acc[mt][1] = MFMA16(kv[mt], bf1, acc[mt][1]);
            }
        }
        // epilogue: raw C-fragment partials, fp16, coalesced b64
        #pragma unroll
        for (int mt = 0; mt < 2; ++mt) {
            #pragma unroll
            for (int cht = 0; cht < 2; ++cht) {
                int segFlat = ((((s * 2 + n) * NPT + pt) * 4 + w) * 2 + mt) * 2 + cht;
                h4 hv;
                hv[0] = (half_t)acc[mt][cht][0];
                hv[1] = (half_t)acc[mt][cht][1];
                hv[2] = (half_t)acc[mt][cht][2];
                hv[3] = (half_t)acc[mt][cht][3];
                *(h4*)(part + (size_t)segFlat * SEG_HALVES + l * 4) = hv;
            }
        }
    } else {
        // ---- conv block: one (n,c); qsf = G * Q * G ----
        int cb = b - NBBIL;
        int n = cb / NC, c = cb % NC;
        half_t* qt = (half_t*)lds;
        half_t* gl = (half_t*)(lds + 9216);
        half_t* dl = (half_t*)(lds + 18432);

        for (int i = tid; i < 512; i += 256) {
            int row = i >> 3, g = i & 7;
            *(h8*)(gl + row * 72 + g * 8) = *(const h8*)(gmat + row * 64 + g * 8);
        }
        const half_t* qsrc = qh16 + (size_t)(n * 24 + c) * NP;
        for (int i = tid; i < 512; i += 256) {
            int row = i >> 3, g = i & 7;
            h8 v = *(const h8*)(qsrc + row * 64 + g * 8);
            #pragma unroll
            for (int k = 0; k < 8; ++k) qt[(g * 8 + k) * 72 + row] = v[k];
        }
        __syncthreads();

        int m0 = w * 16;
        f4 acc1[4];
        #pragma unroll
        for (int nt = 0; nt < 4; ++nt) acc1[nt] = (f4)0.f;
        #pragma unroll
        for (int ks = 0; ks < 2; ++ks) {
            h8 af = *(const h8*)(gl + (size_t)(m0 + (l & 15)) * 72 + ks * 32 + (l >> 4) * 8);
            #pragma unroll
            for (int nt = 0; nt < 4; ++nt) {
                h8 bf = *(const h8*)(qt + (size_t)(nt * 16 + (l & 15)) * 72 + ks * 32 + (l >> 4) * 8);
                acc1[nt] = MFMA16(af, bf, acc1[nt]);
            }
        }
        #pragma unroll
        for (int nt = 0; nt < 4; ++nt)
            #pragma unroll
            for (int r = 0; r < 4; ++r)
                dl[(size_t)(m0 + (l >> 4) * 4 + r) * 72 + nt * 16 + (l & 15)] = (half_t)acc1[nt][r];
        __syncthreads();

        f4 acc2[4];
        #pragma unroll
        for (int nt = 0; nt < 4; ++nt) acc2[nt] = (f4)0.f;
        #pragma unroll
        for (int ks = 0; ks < 2; ++ks) {
            h8 af = *(const h8*)(dl + (size_t)(m0 + (l & 15)) * 72 + ks * 32 + (l >> 4) * 8);
            #pragma unroll
            for (int nt = 0; nt < 4; ++nt) {
                h8 bf = *(const h8*)(gl + (size_t)(nt * 16 + (l & 15)) * 72 + ks * 32 + (l >> 4) * 8);
                acc2[nt] = MFMA16(af, bf, acc2[nt]);
            }
        }
        float* dst = qsf + (size_t)(n * NC + c) * NP;
        #pragma unroll
        for (int nt = 0; nt < 4; ++nt)
            #pragma unroll
            for (int r = 0; r < 4; ++r)
                dst[(size_t)(m0 + (l >> 4) * 4 + r) * 64 + nt * 16 + (l & 15)] = acc2[nt][r];
    }
}

// L2+L3 merged: reduce fp16 partials over s, then per-pixel softmax update.
// 64 blocks, one per (n, pt): 16 consecutive segments per s-slice.
__global__ __launch_bounds__(256) void reduce_update_kernel(
    const half_t* __restrict__ part, const float* __restrict__ ut_,
    const float* __restrict__ qsf, float* __restrict__ outq,
    half_t* __restrict__ qh16)
{
    __shared__ float red[4096];    // 16 segs * 256
    int rb = blockIdx.x;           // [0,64)
    int tid = threadIdx.x;
    int n = rb & 1, pt = rb >> 1;

    float acc[16];
    #pragma unroll
    for (int k = 0; k < 16; ++k) acc[k] = 0.f;
    for (int s = 0; s < SQ; ++s) {
        size_t base = (size_t)(((s * 2 + n) * NPT + pt) * 16) * SEG_HALVES;
        #pragma unroll
        for (int k = 0; k < 4; ++k) {
            h4 v = *(const h4*)(part + base + (size_t)(k * 256 + tid) * 4);
            acc[k*4+0] += (float)v[0]; acc[k*4+1] += (float)v[1];
            acc[k*4+2] += (float)v[2]; acc[k*4+3] += (float)v[3];
        }
    }
    #pragma unroll
    for (int k = 0; k < 4; ++k)
        *(f4*)(red + (k * 256 + tid) * 4) =
            (f4){acc[k*4+0], acc[k*4+1], acc[k*4+2], acc[k*4+3]};
    __syncthreads();

    if (tid < PTILE) {
        int pp = tid;
        int p = pt * PTILE + pp;
        int gid = n * NP + p;
        int mt_g = pp >> 4;                // 0..7
        int wv = mt_g >> 1, mtl = mt_g & 1;
        int mrow = pp & 15;
        int lg = mrow >> 2, reg = mrow & 3;
        int segL = wv * 4 + mtl * 2;       // + cht

        float lg_[NC], e[NC];
        const float* ut = ut_ + (size_t)gid * 24;
        const float* qs = qsf + (size_t)n * NC * NP + p;
        float m = -1e30f;
        #pragma unroll
        for (int c = 0; c < NC; ++c) {
            int cht = c >> 4, chL = c & 15;
            float qb = red[(segL + cht) * 256 + (lg * 16 + chL) * 4 + reg];
            float li = ut[c] + 4.0f * qb + 2.0f * qs[c * NP];
            lg_[c] = li;
            m = fmaxf(m, li);
        }
        float ssum = 0.f;
        #pragma unroll
        for (int c = 0; c < NC; ++c) { e[c] = EXP2F(L2E * (lg_[c] - m)); ssum += e[c]; }
        float inv = 1.0f / ssum;
        #pragma unroll
        for (int c = 0; c < NC; ++c) {
            float qv = e[c] * inv;
            outq[(size_t)(n * NC + c) * NP + p] = qv;
            qh16[(size_t)(n * 24 + c) * NP + p] = (half_t)qv;
        }
    }
}

extern "C" void kernel_launch(void* const* d_in, const int* in_sizes, int n_in,
                              void* d_out, int out_size, void* d_ws, size_t ws_size,
                              hipStream_t stream)
{
    const float* unary = (const float*)d_in[0];
    const float* ref   = (const float*)d_in[1];
    const float* kstd  = (const float*)d_in[3];
    float* ws   = (float*)d_ws;
    float* outq = (float*)d_out;

    const float*  qfeatA = ws + OFF_QFEAT;
    const float*  qsoa   = ws + OFF_QSOA;
    float*        ut     = ws + OFF_UT;
    float*        qsf    = ws + OFF_QSF;
    const half_t* gmat   = (const half_t*)(ws + OFF_G);
    half_t*       qh16   = (half_t*)(ws + OFF_QH16);
    half_t*       part   = (half_t*)(ws + OFF_PART);

    setup_kernel<<<32, 256, 0, stream>>>(unary, ref, kstd, ws, outq);
    for (int it = 0; it < 5; ++it) {
        bilat_conv_kernel<<<NBBIL + NBCONV, 256, 0, stream>>>(
            qfeatA, qsoa, qh16, gmat, part, qsf);
        reduce_update_kernel<<<64, 256, 0, stream>>>(part, ut, qsf, outq, qh16);
    }
}